// Round 6
// baseline (148.312 us; speedup 1.0000x reference)
//
#include <hip/hip_runtime.h>
#include <hip/hip_bf16.h>

// FullAttention fwd, B=4 L=S=2048 H=8 E=D=64, fp32 in/out.
// Round 15: break the 2-phase ~607 TF structure ceiling via occupancy.
// R14 measured 605 TF effective == the known 2-phase {read->bar->stage->
// compute->bar} ceiling with 2 waves/SIMD. This round: 4 waves/block,
// KVBLK=128 (wave w owns s-window w*32; all R6 swizzle formulas are
// wave-generic -- g(r), gk depend only on lane/p), qt=2 so regs ~110 < 128
// => 4 waves/SIMD under __launch_bounds__(256,4). Grid 2048 = 8 blocks/CU
// = 2 clean generations. Barriers per tile halve per s-element. f16 +
// cvt_pkrtz pack + ones-MFMA lsum + XCD swizzle kept from R14.

#define BNUM 4
#define LLEN 2048
#define SLEN 2048
#define HNUM 8
#define EDIM 64

typedef __attribute__((ext_vector_type(8))) short s16x8;     // raw 8x16-bit container
typedef __attribute__((ext_vector_type(8))) _Float16 hf16x8; // f16 MFMA operand
typedef __attribute__((ext_vector_type(2))) __fp16 fp16x2;   // cvt_pkrtz result type
typedef __attribute__((ext_vector_type(4))) float f32x4;

__device__ __forceinline__ short f2h(float f) {
    union { _Float16 h; short s; } u;
    u.h = (_Float16)f;
    return u.s;
}

// pack 8 floats -> 8 f16 (RTZ) in 4 instructions
__device__ __forceinline__ s16x8 pk8(float4 a, float4 b) {
    union { fp16x2 h[4]; s16x8 v; } u;
    u.h[0] = __builtin_amdgcn_cvt_pkrtz(a.x, a.y);
    u.h[1] = __builtin_amdgcn_cvt_pkrtz(a.z, a.w);
    u.h[2] = __builtin_amdgcn_cvt_pkrtz(b.x, b.y);
    u.h[3] = __builtin_amdgcn_cvt_pkrtz(b.z, b.w);
    return u.v;
}

#if __has_builtin(__builtin_amdgcn_global_load_lds)
#define HAVE_GLL 1
#else
#define HAVE_GLL 0
#endif

__device__ __forceinline__ void stage16(const short* g, short* l) {
#if HAVE_GLL
    __builtin_amdgcn_global_load_lds(
        (const __attribute__((address_space(1))) void*)g,
        (__attribute__((address_space(3))) void*)l, 16, 0, 0);
#else
    *(s16x8*)l = *(const s16x8*)g;
#endif
}

// ---- pre-pass: role 0 = K repack, role 1 = V transpose (f16) ----
__global__ __launch_bounds__(256)
void prep(const float* __restrict__ Kg, const float* __restrict__ Vg,
          short* __restrict__ Kc, short* __restrict__ Vt)
{
    __shared__ short tile[EDIM][80];
    if (blockIdx.y == 0) {
        // K [b][s][h][e] fp32 -> Kc [b][h][s][e] f16
        const int t = blockIdx.x * 256 + threadIdx.x;
        const int e8 = t & 7;
        const int tmp = t >> 3;
        const int h = tmp & 7;
        const int tmp2 = tmp >> 3;
        const int s = tmp2 & (SLEN - 1);
        const int b = tmp2 >> 11;
        const float4* src = (const float4*)(Kg + (((size_t)(b * SLEN + s) * HNUM + h) * EDIM + e8 * 8));
        float4 a = src[0], bb = src[1];
        *(s16x8*)(Kc + ((size_t)((b * HNUM + h) * SLEN + s) * EDIM + e8 * 8)) = pk8(a, bb);
    } else {
        // V [b][s][h][d] fp32 -> Vt [b][h][d][s] f16 (64x64 tile transpose)
        if (blockIdx.x >= 1024) return;
        const int x = blockIdx.x;
        const int s0 = (x & 31) * 64;
        const int bh = x >> 5;
        const int b = bh >> 3, h = bh & 7;
        {
            const int sr = threadIdx.x >> 2, dc = (threadIdx.x & 3) * 16;
            const float4* src = (const float4*)(Vg + (((size_t)(b * SLEN + s0 + sr) * HNUM + h) * EDIM + dc));
            #pragma unroll
            for (int j4 = 0; j4 < 4; ++j4) {
                float4 a = src[j4];
                tile[dc + j4*4 + 0][sr] = f2h(a.x);
                tile[dc + j4*4 + 1][sr] = f2h(a.y);
                tile[dc + j4*4 + 2][sr] = f2h(a.z);
                tile[dc + j4*4 + 3][sr] = f2h(a.w);
            }
        }
        __syncthreads();
        {
            const int dr = threadIdx.x >> 2, sc = (threadIdx.x & 3) * 16;
            short* dst = Vt + ((size_t)((b * HNUM + h) * EDIM + dr) * SLEN + s0 + sc);
            *(s16x8*)dst       = *(const s16x8*)&tile[dr][sc];
            *(s16x8*)(dst + 8) = *(const s16x8*)&tile[dr][sc + 8];
        }
    }
}

// ---- main kernel: 4 waves, KVBLK=128, qt=2 ----
// LDS: K region [0:8192) shorts = 128 s-rows x 8 chunks(16B), chunk (r,c) at
// r*8 + (c ^ g(r)), g(r) = ((r>>3)&1)*4 + (r&3)   [R6 formula, wave-generic].
// V region [8192:16384) = 4 panels (per-wave 32-s window), panel = 64 d-rows
// x 4 chunks(16B), chunk (d,c) at d*4 + (c ^ (d&3)) [R6 formula, wave-generic].
__global__ __launch_bounds__(256, 4)
void fa_fwd(const float* __restrict__ Qg, const short* __restrict__ Kc,
            const short* __restrict__ Vt, float* __restrict__ Og)
{
    __shared__ short sKV[16384];   // 32 KB; epilogue reuses as sO (32 x 68 f32)
    __shared__ float sL[4][32];

    const int tid  = threadIdx.x;
    const int wave = tid >> 6;    // s-window index {0,1,2,3}
    const int lane = tid & 63;
    const int m    = lane & 15;
    const int quad = lane >> 4;

    // XCD-aware decode: XCD j gets logical ids [j*256,(j+1)*256) = 4 (b,h)
    // panels (2 MB f16 K/V) -> L2-resident staging.
    const int lin  = (int)blockIdx.x;
    const int logi = ((lin & 7) << 8) + (lin >> 3);   // nwg=2048, nwg/8=256
    const int qx = logi & 63;
    const int h  = (logi >> 6) & 7;
    const int b  = logi >> 9;
    const int qbase = qx * 32;
    const int bh = b * HNUM + h;

    const short* Kbh = Kc + (size_t)bh * SLEN * EDIM;
    const short* Vbh = Vt + (size_t)bh * EDIM * SLEN;

    // ---- staging bases (R6 formulas, wave-generic; p-parity folded) ----
    const int l3 = lane >> 3;
    const int ksrcE = (wave * 32 + l3) * EDIM + ((lane & 7) ^ (l3 & 3)) * 8;        // p even
    const int ksrcO = (wave * 32 + l3) * EDIM + ((lane & 7) ^ (4 + (l3 & 3))) * 8;  // p odd
    const int vsrcB = (lane >> 2) * SLEN + wave * 32 + ((lane & 3) ^ ((lane >> 2) & 3)) * 8;
    short* kdstB = sKV + (wave * 256 + lane) * 8;
    short* vdstB = sKV + 8192 + (wave * 256 + lane) * 8;

#define STAGE_TILE(s0)                                                        \
    do {                                                                      \
        _Pragma("unroll")                                                     \
        for (int p = 0; p < 4; ++p) {                                         \
            const int ks = ((p & 1) ? ksrcO : ksrcE) + (p >> 1) * 1024 + (p & 1) * 512; \
            stage16(Kbh + (size_t)(s0) * EDIM + ks, kdstB + p * 512);         \
            stage16(Vbh + (s0) + vsrcB + p * 16 * SLEN, vdstB + p * 512);     \
        }                                                                     \
    } while (0)

    // ---- Q fragments (B-op: B[k=e=kb*32+quad*8+j][n=q=qt*16+m]), prescaled ----
    const float csc = 0.18033688011112042f;   // (1/sqrt(64)) * log2(e)
    hf16x8 qfrag[2][2];
    #pragma unroll
    for (int qt = 0; qt < 2; ++qt)
        #pragma unroll
        for (int kb = 0; kb < 2; ++kb) {
            const float* qp = Qg + ((size_t)(b * LLEN + qbase + qt * 16 + m) * HNUM + h) * EDIM
                              + kb * 32 + quad * 8;
            float4 x0 = *(const float4*)qp;
            float4 x1 = *(const float4*)(qp + 4);
            float4 y0 = {x0.x*csc, x0.y*csc, x0.z*csc, x0.w*csc};
            float4 y1 = {x1.x*csc, x1.y*csc, x1.z*csc, x1.w*csc};
            union { s16x8 s; hf16x8 h; } u;
            u.s = pk8(y0, y1);
            qfrag[qt][kb] = u.h;
        }

    // ---- frag read offsets (R6 formulas, wave-generic) ----
    const int gk  = ((m >> 2) & 1) * 4 + (m & 3);
    const int pi0 = 8 * (m >> 2) + (m & 3);
    const int kOff00 = (wave * 32 + pi0)     * 64 + ((quad)     ^ gk) * 8;
    const int kOff01 = (wave * 32 + pi0)     * 64 + ((4 + quad) ^ gk) * 8;
    const int kOff10 = (wave * 32 + pi0 + 4) * 64 + ((quad)     ^ gk) * 8;
    const int kOff11 = (wave * 32 + pi0 + 4) * 64 + ((4 + quad) ^ gk) * 8;
    const int vOffB  = 8192 + wave * 2048 + m * 32 + ((quad ^ (m & 3)) * 8);

    // all-ones f16 B-operand for the row-sum MFMA
    hf16x8 vones;
    #pragma unroll
    for (int j = 0; j < 8; ++j) vones[j] = (_Float16)1.0f;

    f32x4 oacc[2][4];   // [qt][dt] -- 32 acc regs
    f32x4 lacc[2];      // row-sum accumulators -- 8 acc regs
    #pragma unroll
    for (int i = 0; i < 2; ++i) {
        #pragma unroll
        for (int j = 0; j < 4; ++j) oacc[i][j] = (f32x4){0.f, 0.f, 0.f, 0.f};
        lacc[i] = (f32x4){0.f, 0.f, 0.f, 0.f};
    }

    STAGE_TILE(0);
    __syncthreads();   // tile 0 resident

    for (int s0 = 0; s0 < SLEN; s0 += 128) {
        // ---- LDS -> registers (balanced b128, conflict-free) ----
        hf16x8 kf00 = *(const hf16x8*)(sKV + kOff00);
        hf16x8 kf01 = *(const hf16x8*)(sKV + kOff01);
        hf16x8 kf10 = *(const hf16x8*)(sKV + kOff10);
        hf16x8 kf11 = *(const hf16x8*)(sKV + kOff11);
        hf16x8 vf0 = *(const hf16x8*)(sKV + vOffB);
        hf16x8 vf1 = *(const hf16x8*)(sKV + vOffB + 512);
        hf16x8 vf2 = *(const hf16x8*)(sKV + vOffB + 1024);
        hf16x8 vf3 = *(const hf16x8*)(sKV + vOffB + 1536);

        __syncthreads();   // barrier1: all waves hold the tile in regs

        if (s0 + 128 < SLEN) STAGE_TILE(s0 + 128);   // DMA next; overlaps compute

        // ---- compute: 18 MFMAs per wave per tile ----
        #pragma unroll
        for (int qt = 0; qt < 2; ++qt) {
            f32x4 a0 = {0.f, 0.f, 0.f, 0.f};
            f32x4 a1 = {0.f, 0.f, 0.f, 0.f};
            a0 = __builtin_amdgcn_mfma_f32_16x16x32_f16(kf00, qfrag[qt][0], a0, 0, 0, 0);
            a0 = __builtin_amdgcn_mfma_f32_16x16x32_f16(kf01, qfrag[qt][1], a0, 0, 0, 0);
            a1 = __builtin_amdgcn_mfma_f32_16x16x32_f16(kf10, qfrag[qt][0], a1, 0, 0, 0);
            a1 = __builtin_amdgcn_mfma_f32_16x16x32_f16(kf11, qfrag[qt][1], a1, 0, 0, 0);
            // a0[r]=S[s_local=8*quad+r][q], a1[r]=S[s_local=8*quad+4+r][q]
            float p0 = __builtin_amdgcn_exp2f(a0[0]);
            float p1 = __builtin_amdgcn_exp2f(a0[1]);
            float p2 = __builtin_amdgcn_exp2f(a0[2]);
            float p3 = __builtin_amdgcn_exp2f(a0[3]);
            float p4 = __builtin_amdgcn_exp2f(a1[0]);
            float p5 = __builtin_amdgcn_exp2f(a1[1]);
            float p6 = __builtin_amdgcn_exp2f(a1[2]);
            float p7 = __builtin_amdgcn_exp2f(a1[3]);
            // A-op: A[q=m][k=s_local=quad*8+j], packed in 4 instrs
            union { fp16x2 h2[4]; hf16x8 v; } pu;
            pu.h2[0] = __builtin_amdgcn_cvt_pkrtz(p0, p1);
            pu.h2[1] = __builtin_amdgcn_cvt_pkrtz(p2, p3);
            pu.h2[2] = __builtin_amdgcn_cvt_pkrtz(p4, p5);
            pu.h2[3] = __builtin_amdgcn_cvt_pkrtz(p6, p7);
            hf16x8 pf = pu.v;
            // row-sum over the wave's 32-s window via ones-MFMA (exact, f32 acc)
            lacc[qt] = __builtin_amdgcn_mfma_f32_16x16x32_f16(pf, vones, lacc[qt], 0, 0, 0);
            oacc[qt][0] = __builtin_amdgcn_mfma_f32_16x16x32_f16(pf, vf0, oacc[qt][0], 0, 0, 0);
            oacc[qt][1] = __builtin_amdgcn_mfma_f32_16x16x32_f16(pf, vf1, oacc[qt][1], 0, 0, 0);
            oacc[qt][2] = __builtin_amdgcn_mfma_f32_16x16x32_f16(pf, vf2, oacc[qt][2], 0, 0, 0);
            oacc[qt][3] = __builtin_amdgcn_mfma_f32_16x16x32_f16(pf, vf3, oacc[qt][3], 0, 0, 0);
        }

        __syncthreads();   // barrier2: DMA drained after compute; next tile ready
    }

    // ---- epilogue: lacc holds per-q row-sums (C[row=quad*4+r][col=m], all m equal) ----
    if (m == 0) {
        #pragma unroll
        for (int qt = 0; qt < 2; ++qt)
            #pragma unroll
            for (int r = 0; r < 4; ++r)
                sL[wave][qt * 16 + quad * 4 + r] = lacc[qt][r];
    }
    __syncthreads();

    float* sO = (float*)sKV;   // 32 rows x 68 floats = 8704 B
    #pragma unroll
    for (int w = 0; w < 4; ++w) {
        if (wave == w) {
            #pragma unroll
            for (int qt = 0; qt < 2; ++qt)
                #pragma unroll
                for (int dt = 0; dt < 4; ++dt)
                    #pragma unroll
                    for (int r = 0; r < 4; ++r) {
                        const int idx = (qt * 16 + quad * 4 + r) * 68 + dt * 16 + m;
                        if (w == 0) sO[idx] = oacc[qt][dt][r];
                        else        sO[idx] += oacc[qt][dt][r];
                    }
        }
        __syncthreads();
    }

    {
        const int q = tid >> 3;            // [0,32)
        const int dcol = (tid & 7) * 8;
        const float l = (sL[0][q] + sL[1][q]) + (sL[2][q] + sL[3][q]);
        const float inv = 1.0f / l;
        float* orow = Og + ((size_t)(b * LLEN + qbase + q) * HNUM + h) * EDIM + dcol;
        float4 v0 = *(const float4*)(sO + q * 68 + dcol);
        float4 v1 = *(const float4*)(sO + q * 68 + dcol + 4);
        v0.x *= inv; v0.y *= inv; v0.z *= inv; v0.w *= inv;
        v1.x *= inv; v1.y *= inv; v1.z *= inv; v1.w *= inv;
        *(float4*)(orow)     = v0;
        *(float4*)(orow + 4) = v1;
    }
}

extern "C" void kernel_launch(void* const* d_in, const int* in_sizes, int n_in,
                              void* d_out, int out_size, void* d_ws, size_t ws_size,
                              hipStream_t stream) {
    const float* Q = (const float*)d_in[0];
    const float* K = (const float*)d_in[1];
    const float* V = (const float*)d_in[2];
    float* O = (float*)d_out;

    const size_t NE = (size_t)BNUM * LLEN * HNUM * EDIM;   // 4,194,304
    short* Kc = (short*)d_ws;
    short* Vt = Kc + NE;

    prep<<<dim3(2048, 2), dim3(256), 0, stream>>>(K, V, Kc, Vt);
    fa_fwd<<<dim3(2048), dim3(256), 0, stream>>>(Q, Kc, Vt, O);
}

// Round 8
// 137.219 us; speedup vs baseline: 1.0808x; 1.0808x over previous
//
#include <hip/hip_runtime.h>
#include <hip/hip_bf16.h>

// FullAttention fwd, B=4 L=S=2048 H=8 E=D=64, fp32 in/out.
// Round 17 == Round 16 resubmitted (container infra failed twice; kernel
// re-audited: barrier uniformity, vmcnt ledger, buffer rotation all sound).
// R14 geometry (2 waves, qt=4, KVBLK=64, grid 1024, f16, cvt_pkrtz pack,
// ones-MFMA lsum, XCD swizzle) + T3/T4-style pipelined staging: double-
// buffered LDS (2 x 16 KB), raw s_barrier (no implicit vmcnt(0) drain),
// counted s_waitcnt vmcnt(8) at loop top -- tile t+1's 8 DMA loads stay in
// flight across both barriers, and tile t+2 is staged into the freed buffer
// right after an lgkmcnt(0)-guarded barrier. The DMA gets ~2 compute phases
// to land instead of <1 (the measured 2-phase ceiling mechanism). Last
// iteration peels to vmcnt(0).

#define BNUM 4
#define LLEN 2048
#define SLEN 2048
#define HNUM 8
#define EDIM 64

typedef __attribute__((ext_vector_type(8))) short s16x8;     // raw 8x16-bit container
typedef __attribute__((ext_vector_type(8))) _Float16 hf16x8; // f16 MFMA operand
typedef __attribute__((ext_vector_type(2))) __fp16 fp16x2;   // cvt_pkrtz result type
typedef __attribute__((ext_vector_type(4))) float f32x4;

__device__ __forceinline__ short f2h(float f) {
    union { _Float16 h; short s; } u;
    u.h = (_Float16)f;
    return u.s;
}

// pack 8 floats -> 8 f16 (RTZ) in 4 instructions
__device__ __forceinline__ s16x8 pk8(float4 a, float4 b) {
    union { fp16x2 h[4]; s16x8 v; } u;
    u.h[0] = __builtin_amdgcn_cvt_pkrtz(a.x, a.y);
    u.h[1] = __builtin_amdgcn_cvt_pkrtz(a.z, a.w);
    u.h[2] = __builtin_amdgcn_cvt_pkrtz(b.x, b.y);
    u.h[3] = __builtin_amdgcn_cvt_pkrtz(b.z, b.w);
    return u.v;
}

#if __has_builtin(__builtin_amdgcn_global_load_lds)
#define HAVE_GLL 1
#else
#define HAVE_GLL 0
#endif

__device__ __forceinline__ void stage16(const short* g, short* l) {
#if HAVE_GLL
    __builtin_amdgcn_global_load_lds(
        (const __attribute__((address_space(1))) void*)g,
        (__attribute__((address_space(3))) void*)l, 16, 0, 0);
#else
    *(s16x8*)l = *(const s16x8*)g;
#endif
}

// ---- pre-pass: role 0 = K repack, role 1 = V transpose (f16) ----
__global__ __launch_bounds__(256)
void prep(const float* __restrict__ Kg, const float* __restrict__ Vg,
          short* __restrict__ Kc, short* __restrict__ Vt)
{
    __shared__ short tile[EDIM][80];
    if (blockIdx.y == 0) {
        // K [b][s][h][e] fp32 -> Kc [b][h][s][e] f16
        const int t = blockIdx.x * 256 + threadIdx.x;
        const int e8 = t & 7;
        const int tmp = t >> 3;
        const int h = tmp & 7;
        const int tmp2 = tmp >> 3;
        const int s = tmp2 & (SLEN - 1);
        const int b = tmp2 >> 11;
        const float4* src = (const float4*)(Kg + (((size_t)(b * SLEN + s) * HNUM + h) * EDIM + e8 * 8));
        float4 a = src[0], bb = src[1];
        *(s16x8*)(Kc + ((size_t)((b * HNUM + h) * SLEN + s) * EDIM + e8 * 8)) = pk8(a, bb);
    } else {
        // V [b][s][h][d] fp32 -> Vt [b][h][d][s] f16 (64x64 tile transpose)
        if (blockIdx.x >= 1024) return;
        const int x = blockIdx.x;
        const int s0 = (x & 31) * 64;
        const int bh = x >> 5;
        const int b = bh >> 3, h = bh & 7;
        {
            const int sr = threadIdx.x >> 2, dc = (threadIdx.x & 3) * 16;
            const float4* src = (const float4*)(Vg + (((size_t)(b * SLEN + s0 + sr) * HNUM + h) * EDIM + dc));
            #pragma unroll
            for (int j4 = 0; j4 < 4; ++j4) {
                float4 a = src[j4];
                tile[dc + j4*4 + 0][sr] = f2h(a.x);
                tile[dc + j4*4 + 1][sr] = f2h(a.y);
                tile[dc + j4*4 + 2][sr] = f2h(a.z);
                tile[dc + j4*4 + 3][sr] = f2h(a.w);
            }
        }
        __syncthreads();
        {
            const int dr = threadIdx.x >> 2, sc = (threadIdx.x & 3) * 16;
            short* dst = Vt + ((size_t)((b * HNUM + h) * EDIM + dr) * SLEN + s0 + sc);
            *(s16x8*)dst       = *(const s16x8*)&tile[dr][sc];
            *(s16x8*)(dst + 8) = *(const s16x8*)&tile[dr][sc + 8];
        }
    }
}

// ---- main kernel: R14 geometry + double-buffered pipelined staging ----
// Per buffer (8192 shorts): K [0:4096) = 64 s-rows x 8 chunks(16B), chunk
// (r,c) at r*8 + (c ^ g(r)), g(r) = ((r>>3)&1)*4 + (r&3); V [4096:8192) =
// 2 panels (per-wave 32-s window), 64 d-rows x 4 chunks(16B), chunk (d,c)
// at d*4 + (c ^ (d&3)).  [R6 formulas verbatim]
__global__ __launch_bounds__(128, 2)
void fa_fwd(const float* __restrict__ Qg, const short* __restrict__ Kc,
            const short* __restrict__ Vt, float* __restrict__ Og)
{
    __shared__ short sKV[16384];   // 2 buffers x 16 KB; epilogue reuses as sO
    __shared__ float sL[2][64];

    const int tid  = threadIdx.x;
    const int wave = tid >> 6;    // s-window index {0,1}
    const int lane = tid & 63;
    const int m    = lane & 15;
    const int quad = lane >> 4;

    // XCD-aware decode: XCD j works logical ids [j*128,(j+1)*128) = 4 (b,h)
    // panels (2 MB f16 K/V) -> L2-resident staging.
    const int lin  = (int)blockIdx.x;
    const int logi = ((lin & 7) << 7) + (lin >> 3);   // nwg=1024, nwg/8=128
    const int qx = logi & 31;
    const int h  = (logi >> 5) & 7;
    const int b  = logi >> 8;
    const int qbase = qx * 64;
    const int bh = b * HNUM + h;

    const short* Kbh = Kc + (size_t)bh * SLEN * EDIM;
    const short* Vbh = Vt + (size_t)bh * EDIM * SLEN;

    // ---- staging bases (R6 formulas; p-parity folded) ----
    const int l3 = lane >> 3;
    const int ksrcE = (wave * 32 + l3) * EDIM + ((lane & 7) ^ (l3 & 3)) * 8;        // p even
    const int ksrcO = (wave * 32 + l3) * EDIM + ((lane & 7) ^ (4 + (l3 & 3))) * 8;  // p odd
    const int vsrcB = (lane >> 2) * SLEN + wave * 32 + ((lane & 3) ^ ((lane >> 2) & 3)) * 8;
    short* kdstB = sKV + (wave * 256 + lane) * 8;
    short* vdstB = sKV + 4096 + (wave * 256 + lane) * 8;

#define STAGE_TILE(buf, s0)                                                   \
    do {                                                                      \
        short* kd = kdstB + (buf) * 8192;                                     \
        short* vd = vdstB + (buf) * 8192;                                     \
        _Pragma("unroll")                                                     \
        for (int p = 0; p < 4; ++p) {                                         \
            const int ks = ((p & 1) ? ksrcO : ksrcE) + (p >> 1) * 1024 + (p & 1) * 512; \
            stage16(Kbh + (size_t)(s0) * EDIM + ks, kd + p * 512);            \
            stage16(Vbh + (s0) + vsrcB + p * 16 * SLEN, vd + p * 512);        \
        }                                                                     \
    } while (0)

    // prologue: stage tiles 0 and 1 into the two buffers (16 loads in flight)
    STAGE_TILE(0, 0);
    asm volatile("" ::: "memory");
    STAGE_TILE(1, 64);
    asm volatile("" ::: "memory");

    // ---- Q fragments (B-op: B[k=e=kb*32+quad*8+j][n=q=qt*16+m]), prescaled ----
    const float csc = 0.18033688011112042f;   // (1/sqrt(64)) * log2(e)
    hf16x8 qfrag[4][2];
    #pragma unroll
    for (int qt = 0; qt < 4; ++qt)
        #pragma unroll
        for (int kb = 0; kb < 2; ++kb) {
            const float* qp = Qg + ((size_t)(b * LLEN + qbase + qt * 16 + m) * HNUM + h) * EDIM
                              + kb * 32 + quad * 8;
            float4 x0 = *(const float4*)qp;
            float4 x1 = *(const float4*)(qp + 4);
            float4 y0 = {x0.x*csc, x0.y*csc, x0.z*csc, x0.w*csc};
            float4 y1 = {x1.x*csc, x1.y*csc, x1.z*csc, x1.w*csc};
            union { s16x8 s; hf16x8 hh; } u;
            u.s = pk8(y0, y1);
            qfrag[qt][kb] = u.hh;
        }

    // ---- frag read offsets (R6 formulas verbatim, wave in {0,1}) ----
    const int gk  = ((m >> 2) & 1) * 4 + (m & 3);
    const int pi0 = 8 * (m >> 2) + (m & 3);
    const int kOff00 = (wave * 32 + pi0)     * 64 + ((quad)     ^ gk) * 8;
    const int kOff01 = (wave * 32 + pi0)     * 64 + ((4 + quad) ^ gk) * 8;
    const int kOff10 = (wave * 32 + pi0 + 4) * 64 + ((quad)     ^ gk) * 8;
    const int kOff11 = (wave * 32 + pi0 + 4) * 64 + ((4 + quad) ^ gk) * 8;
    const int vOffB  = 4096 + wave * 2048 + m * 32 + ((quad ^ (m & 3)) * 8);

    // all-ones f16 B-operand for the row-sum MFMA
    hf16x8 vones;
    #pragma unroll
    for (int j = 0; j < 8; ++j) vones[j] = (_Float16)1.0f;

    f32x4 oacc[4][4];   // [qt][dt]
    f32x4 lacc[4];      // row-sum accumulators
    #pragma unroll
    for (int i = 0; i < 4; ++i) {
        #pragma unroll
        for (int j = 0; j < 4; ++j) oacc[i][j] = (f32x4){0.f, 0.f, 0.f, 0.f};
        lacc[i] = (f32x4){0.f, 0.f, 0.f, 0.f};
    }

    for (int s0 = 0; s0 < SLEN; s0 += 64) {
        const int t = s0 >> 6;            // 0..31
        const int bufo = (t & 1) * 8192;

        // tile t's 8 DMA loads done; tile t+1's 8 may stay in flight
        if (t < SLEN / 64 - 1) asm volatile("s_waitcnt vmcnt(8)" ::: "memory");
        else                   asm volatile("s_waitcnt vmcnt(0)" ::: "memory");
        __builtin_amdgcn_s_barrier();     // all waves: tile t resident

        // ---- LDS -> registers (balanced b128, conflict-free) ----
        hf16x8 kf00 = *(const hf16x8*)(sKV + bufo + kOff00);
        hf16x8 kf01 = *(const hf16x8*)(sKV + bufo + kOff01);
        hf16x8 kf10 = *(const hf16x8*)(sKV + bufo + kOff10);
        hf16x8 kf11 = *(const hf16x8*)(sKV + bufo + kOff11);
        hf16x8 vf0 = *(const hf16x8*)(sKV + bufo + vOffB);
        hf16x8 vf1 = *(const hf16x8*)(sKV + bufo + vOffB + 512);
        hf16x8 vf2 = *(const hf16x8*)(sKV + bufo + vOffB + 1024);
        hf16x8 vf3 = *(const hf16x8*)(sKV + bufo + vOffB + 1536);

        asm volatile("s_waitcnt lgkmcnt(0)" ::: "memory");  // my reads complete
        __builtin_amdgcn_sched_barrier(0);
        __builtin_amdgcn_s_barrier();     // all waves done reading buf[t&1]

        if (t + 2 < SLEN / 64) STAGE_TILE(t & 1, s0 + 128);  // refill freed buffer

        // ---- compute: 36 MFMAs per wave per tile ----
        #pragma unroll
        for (int qt = 0; qt < 4; ++qt) {
            f32x4 a0 = {0.f, 0.f, 0.f, 0.f};
            f32x4 a1 = {0.f, 0.f, 0.f, 0.f};
            a0 = __builtin_amdgcn_mfma_f32_16x16x32_f16(kf00, qfrag[qt][0], a0, 0, 0, 0);
            a0 = __builtin_amdgcn_mfma_f32_16x16x32_f16(kf01, qfrag[qt][1], a0, 0, 0, 0);
            a1 = __builtin_amdgcn_mfma_f32_16x16x32_f16(kf10, qfrag[qt][0], a1, 0, 0, 0);
            a1 = __builtin_amdgcn_mfma_f32_16x16x32_f16(kf11, qfrag[qt][1], a1, 0, 0, 0);
            // a0[r]=S[s_local=8*quad+r][q], a1[r]=S[s_local=8*quad+4+r][q]
            float p0 = __builtin_amdgcn_exp2f(a0[0]);
            float p1 = __builtin_amdgcn_exp2f(a0[1]);
            float p2 = __builtin_amdgcn_exp2f(a0[2]);
            float p3 = __builtin_amdgcn_exp2f(a0[3]);
            float p4 = __builtin_amdgcn_exp2f(a1[0]);
            float p5 = __builtin_amdgcn_exp2f(a1[1]);
            float p6 = __builtin_amdgcn_exp2f(a1[2]);
            float p7 = __builtin_amdgcn_exp2f(a1[3]);
            // A-op: A[q=m][k=s_local=quad*8+j], packed in 4 instrs
            union { fp16x2 h2[4]; hf16x8 v; } pu;
            pu.h2[0] = __builtin_amdgcn_cvt_pkrtz(p0, p1);
            pu.h2[1] = __builtin_amdgcn_cvt_pkrtz(p2, p3);
            pu.h2[2] = __builtin_amdgcn_cvt_pkrtz(p4, p5);
            pu.h2[3] = __builtin_amdgcn_cvt_pkrtz(p6, p7);
            hf16x8 pf = pu.v;
            // row-sum over the wave's 32-s window via ones-MFMA (exact, f32 acc)
            lacc[qt] = __builtin_amdgcn_mfma_f32_16x16x32_f16(pf, vones, lacc[qt], 0, 0, 0);
            oacc[qt][0] = __builtin_amdgcn_mfma_f32_16x16x32_f16(pf, vf0, oacc[qt][0], 0, 0, 0);
            oacc[qt][1] = __builtin_amdgcn_mfma_f32_16x16x32_f16(pf, vf1, oacc[qt][1], 0, 0, 0);
            oacc[qt][2] = __builtin_amdgcn_mfma_f32_16x16x32_f16(pf, vf2, oacc[qt][2], 0, 0, 0);
            oacc[qt][3] = __builtin_amdgcn_mfma_f32_16x16x32_f16(pf, vf3, oacc[qt][3], 0, 0, 0);
        }
    }

    // ---- epilogue: lacc holds per-q row-sums (C[row=quad*4+r][col=m], all m equal) ----
    if (m == 0) {
        #pragma unroll
        for (int qt = 0; qt < 4; ++qt)
            #pragma unroll
            for (int r = 0; r < 4; ++r)
                sL[wave][qt * 16 + quad * 4 + r] = lacc[qt][r];
    }
    __syncthreads();

    float* sO = (float*)sKV;   // 64 rows x 68 floats = 17408 B
    if (wave == 0) {
        #pragma unroll
        for (int qt = 0; qt < 4; ++qt)
            #pragma unroll
            for (int dt = 0; dt < 4; ++dt)
                #pragma unroll
                for (int r = 0; r < 4; ++r)
                    sO[(qt * 16 + quad * 4 + r) * 68 + dt * 16 + m] = oacc[qt][dt][r];
    }
    __syncthreads();
    if (wave == 1) {
        #pragma unroll
        for (int qt = 0; qt < 4; ++qt)
            #pragma unroll
            for (int dt = 0; dt < 4; ++dt)
                #pragma unroll
                for (int r = 0; r < 4; ++r)
                    sO[(qt * 16 + quad * 4 + r) * 68 + dt * 16 + m] += oacc[qt][dt][r];
    }
    __syncthreads();

    {
        const int q = tid >> 1;            // [0,64)
        const int dcol = (tid & 1) * 32;
        const float l = sL[0][q] + sL[1][q];
        const float inv = 1.0f / l;
        float* orow = Og + ((size_t)(b * LLEN + qbase + q) * HNUM + h) * EDIM + dcol;
        #pragma unroll
        for (int j = 0; j < 8; ++j) {
            float4 v = *(const float4*)(sO + q * 68 + dcol + j * 4);
            v.x *= inv; v.y *= inv; v.z *= inv; v.w *= inv;
            *(float4*)(orow + j * 4) = v;
        }
    }
}

extern "C" void kernel_launch(void* const* d_in, const int* in_sizes, int n_in,
                              void* d_out, int out_size, void* d_ws, size_t ws_size,
                              hipStream_t stream) {
    const float* Q = (const float*)d_in[0];
    const float* K = (const float*)d_in[1];
    const float* V = (const float*)d_in[2];
    float* O = (float*)d_out;

    const size_t NE = (size_t)BNUM * LLEN * HNUM * EDIM;   // 4,194,304
    short* Kc = (short*)d_ws;
    short* Vt = Kc + NE;

    prep<<<dim3(2048, 2), dim3(256), 0, stream>>>(K, V, Kc, Vt);
    fa_fwd<<<dim3(1024), dim3(128), 0, stream>>>(Q, Kc, Vt, O);
}